// Round 4
// baseline (730.721 us; speedup 1.0000x reference)
//
#include <hip/hip_runtime.h>
#include <hip/hip_bf16.h>
#include <hip/hip_fp16.h>

// CompressedFP8Linear — R4 DIAGNOSTIC BISECT.
// out[128,8192] = x[128,8192] @ (w*scale)[8192,8192]^T + bias
//
// R4 journal:
//  - Threshold fixed at 0.146875 = max|ref|/50 every round => ref max 7.34 =>
//    harness uses setup distributions; the 514 is garbage IN MY OUTPUT.
//  - absmax bit-identical across R1(single-bf16,KT64)/R2(hi-lo split,KT32)/
//    R3(size-ID+runtime scale flag): inconsistent with any single-bug model I
//    can write. => bisect with an exact fp32 VALU GEMM, zero MFMA, zero
//    atomics, every input assumption runtime-tested.
//  - Input ID by SIZE RANK (robust to element/byte units and any order):
//    largest=weight, 2nd=x, rest={scale,bias}.
//  - scale-vs-bias by content: scale strictly in [1e-3,2e-2] -> all samples in
//    (1e-4,0.5). Bias (any encoding) fails: f32 has negatives; f16/bf16
//    misreads give exponent garbage.
//  - bias dtype probed f16 -> bf16 -> f32:
//      true f16:  f16 read small ✓ (stop).
//      true bf16: f16 read of bf16 bits ~1.0-1.3 ✗; bf16 read small ✓.
//      true f32:  f16/bf16 reads hit low-half mantissa bits -> random
//                 exponents, P(all 64 small) ~1e-20 ✗✗; f32 fallback ✓.
//  - No MFMA in this kernel: if counters show MFMA activity, or absmax is
//    again exactly 514.0234, the bench replayed a stale binary.

namespace {
constexpr int MM = 128;
constexpr int NN = 8192;
constexpr int KK = 8192;
constexpr int NT = 32;     // n-tile per block -> 256 blocks
constexpr int KT = 32;     // k per LDS stage
}

__global__ __launch_bounds__(256, 2)
void diag_gemm(const float* __restrict__ x, const float* __restrict__ w,
               const float* __restrict__ c1, const float* __restrict__ c2,
               float* __restrict__ out)
{
    __shared__ float lxT[KT][MM + 4];   // x tile, transposed [k][m], padded
    __shared__ float lwT[KT][NT + 4];   // w tile, transposed [k][n], padded
    __shared__ float s_scale[NT], s_bias[NT];
    __shared__ int s_c1_is_scale;
    __shared__ int s_bias_kind;         // 0=f16, 1=bf16, 2=f32

    const int tid = threadIdx.x;
    const int nblk = blockIdx.x * NT;

    // ---- runtime content-based disambiguation (thread 0) ----
    if (tid == 0) {
        int ok1 = 1;
        for (int i = 0; i < 64; ++i) {          // idx<=4032: within 16KB min buf
            float v = c1[i * 64];
            if (!(v > 1e-4f && v < 0.5f)) { ok1 = 0; break; }
        }
        s_c1_is_scale = ok1;
        const void* bp = ok1 ? (const void*)c2 : (const void*)c1;
        int kind = 2;
        {
            const __half* h = (const __half*)bp;
            int good = 1;
            for (int i = 0; i < 64; ++i) {
                float v = __half2float(h[i * 64]);
                if (!(v < 0.5f && v > -0.5f)) { good = 0; break; }  // NaN -> fail
            }
            if (good) kind = 0;
        }
        if (kind == 2) {
            const __hip_bfloat16* h = (const __hip_bfloat16*)bp;
            int good = 1;
            for (int i = 0; i < 64; ++i) {
                float v = __bfloat162float(h[i * 64]);
                if (!(v < 0.5f && v > -0.5f)) { good = 0; break; }
            }
            if (good) kind = 1;
        }
        s_bias_kind = kind;
    }
    __syncthreads();

    const float* scalep = s_c1_is_scale ? c1 : c2;
    const void*  biasp  = s_c1_is_scale ? (const void*)c2 : (const void*)c1;
    if (tid < NT) {
        s_scale[tid] = scalep[nblk + tid];
        float b;
        if (s_bias_kind == 0)      b = __half2float(((const __half*)biasp)[nblk + tid]);
        else if (s_bias_kind == 1) b = __bfloat162float(((const __hip_bfloat16*)biasp)[nblk + tid]);
        else                       b = ((const float*)biasp)[nblk + tid];
        s_bias[tid] = b;
    }

    // micro-tile: 4m x 4n per thread (128x32 block tile / 256 threads)
    const int tm = (tid & 31) * 4;
    const int tn = (tid >> 5) * 4;
    float acc[4][4] = {};

    for (int k0 = 0; k0 < KK; k0 += KT) {
        // ---- global loads: x tile 128x32 (4 float4/thread), w tile 32x32 ----
        float4 xv[4], wv;
#pragma unroll
        for (int j = 0; j < 4; ++j) {
            int idx = tid + 256 * j;
            int r = idx >> 3, c4 = idx & 7;
            xv[j] = *(const float4*)(x + (size_t)r * KK + k0 + c4 * 4);
        }
        {
            int r = tid >> 3, c4 = tid & 7;
            wv = *(const float4*)(w + (size_t)(nblk + r) * KK + k0 + c4 * 4);
        }

        __syncthreads();   // previous compute done before overwrite

#pragma unroll
        for (int j = 0; j < 4; ++j) {
            int idx = tid + 256 * j;
            int r = idx >> 3, c4 = (idx & 7) * 4;
            lxT[c4 + 0][r] = xv[j].x;
            lxT[c4 + 1][r] = xv[j].y;
            lxT[c4 + 2][r] = xv[j].z;
            lxT[c4 + 3][r] = xv[j].w;
        }
        {
            int r = tid >> 3, c4 = (tid & 7) * 4;
            lwT[c4 + 0][r] = wv.x;
            lwT[c4 + 1][r] = wv.y;
            lwT[c4 + 2][r] = wv.z;
            lwT[c4 + 3][r] = wv.w;
        }

        __syncthreads();

        // ---- exact fp32 accumulate ----
#pragma unroll
        for (int k = 0; k < KT; ++k) {
            float4 xm = *(const float4*)&lxT[k][tm];   // (MM+4)%4==0: aligned
            float4 wn = *(const float4*)&lwT[k][tn];   // (NT+4)%4==0: aligned
            const float* xs = (const float*)&xm;
            const float* ws = (const float*)&wn;
#pragma unroll
            for (int i = 0; i < 4; ++i)
#pragma unroll
                for (int j = 0; j < 4; ++j)
                    acc[i][j] = fmaf(xs[i], ws[j], acc[i][j]);
        }
    }

    // ---- epilogue: single plain store per output ----
#pragma unroll
    for (int j = 0; j < 4; ++j) {
        const float sc = s_scale[tn + j];
        const float bs = s_bias[tn + j];
#pragma unroll
        for (int i = 0; i < 4; ++i)
            out[(size_t)(tm + i) * NN + nblk + tn + j] = acc[i][j] * sc + bs;
    }
}

extern "C" void kernel_launch(void* const* d_in, const int* in_sizes, int n_in,
                              void* d_out, int out_size, void* d_ws, size_t ws_size,
                              hipStream_t stream) {
    // Size-rank input ID: largest = weight, 2nd largest = x, rest = {scale,bias}
    // (robust to element-count vs byte-count and to any ordering).
    int iw = 0;
    for (int i = 1; i < n_in; ++i) if (in_sizes[i] > in_sizes[iw]) iw = i;
    int ix = -1;
    for (int i = 0; i < n_in; ++i)
        if (i != iw && (ix < 0 || in_sizes[i] > in_sizes[ix])) ix = i;
    const float* c1 = nullptr;
    const float* c2 = nullptr;
    for (int i = 0; i < n_in; ++i) {
        if (i == iw || i == ix) continue;
        if (!c1) c1 = (const float*)d_in[i];
        else     c2 = (const float*)d_in[i];
    }
    const float* w = (const float*)d_in[iw];
    const float* x = (const float*)d_in[ix];
    float* out = (float*)d_out;

    // safety: deterministic zero background even if an indexing bug left gaps
    hipMemsetAsync(d_out, 0, (size_t)out_size * sizeof(float), stream);

    diag_gemm<<<dim3(NN / NT), dim3(256, 1, 1), 0, stream>>>(x, w, c1, c2, out);
}

// Round 5
// 457.855 us; speedup vs baseline: 1.5960x; 1.5960x over previous
//
#include <hip/hip_runtime.h>
#include <hip/hip_bf16.h>
#include <hip/hip_fp16.h>

// CompressedFP8Linear: out[128,8192] = x[128,8192] @ (w*scale)[8192,8192]^T + bias
//
// R5 journal:
//  - R4 PASSED (fp32 VALU diag, 490us, absmax 0.031): input mapping solved =
//    size-RANK (largest=weight, 2nd=x) + device-side content probe for
//    scale-vs-bias and bias dtype. R1-R3 failures were input misID.
//  - R5: same launch-side ID + device probes, MFMA bf16 core (m89/m92-verified
//    layouts). scale<=0.02 -> single bf16 pass error ~0.007 << thr 0.147.
//  - Grid 64 n-tiles x KSPLIT=8 (512 blocks, 2/CU), atomicAdd f32 combine
//    into memset-zeroed d_out.
//  - HBM floor: 268MB weight / 6.3 TB/s = 43us. R4 was 490us.

namespace {
constexpr int NN = 8192;           // output channels
constexpr int KK = 8192;           // reduction dim
constexpr int NT = 128;            // n-tile per block
constexpr int KSPLIT = 8;          // k-split over blockIdx.y, atomic combine
constexpr int KPB = KK / KSPLIT;   // 1024 k per block
constexpr int KT = 64;             // k staged per iteration
constexpr int LDSP = KT + 8;       // pad -> conflict-free b128 LDS access

typedef __attribute__((ext_vector_type(8))) short bf16x8;
typedef __attribute__((ext_vector_type(4))) float f32x4;
}

__global__ __launch_bounds__(256, 2)
void cfp8lin_mfma(const float* __restrict__ x, const float* __restrict__ w,
                  const float* __restrict__ c1, const float* __restrict__ c2,
                  float* __restrict__ out)
{
    __shared__ __align__(16) __hip_bfloat16 lx[128 * LDSP];
    __shared__ __align__(16) __hip_bfloat16 lw[128 * LDSP];
    __shared__ float s_scale[NT];
    __shared__ float s_bias[NT];
    __shared__ int s_c1_is_scale;
    __shared__ int s_bias_kind;        // 0=f16, 1=bf16, 2=f32

    const int tid = threadIdx.x;
    const int n0 = blockIdx.x * NT;
    const int kz = blockIdx.y;
    const int kbase = kz * KPB;

    // ---- runtime content-based disambiguation (verbatim from passing R4) ----
    if (tid == 0) {
        int ok1 = 1;
        for (int i = 0; i < 64; ++i) {         // idx<=4032: within min buffer
            float v = c1[i * 64];
            if (!(v > 1e-4f && v < 0.5f)) { ok1 = 0; break; }
        }
        s_c1_is_scale = ok1;
        const void* bp = ok1 ? (const void*)c2 : (const void*)c1;
        int kind = 2;
        {
            const __half* h = (const __half*)bp;
            int good = 1;
            for (int i = 0; i < 64; ++i) {
                float v = __half2float(h[i * 64]);
                if (!(v < 0.5f && v > -0.5f)) { good = 0; break; }
            }
            if (good) kind = 0;
        }
        if (kind == 2) {
            const __hip_bfloat16* h = (const __hip_bfloat16*)bp;
            int good = 1;
            for (int i = 0; i < 64; ++i) {
                float v = __bfloat162float(h[i * 64]);
                if (!(v < 0.5f && v > -0.5f)) { good = 0; break; }
            }
            if (good) kind = 1;
        }
        s_bias_kind = kind;
    }

    // staging: thread -> (row 0..127, 32-col half)
    const int srow = tid >> 1;
    const int scol = (tid & 1) * 32;

    // compute: 4 waves, each a 64x64 quadrant of the 128x128 C-tile
    const int lane = tid & 63;
    const int wid  = tid >> 6;
    const int wm0  = (wid & 1) * 64;
    const int wn0  = (wid >> 1) * 64;
    const int l16  = lane & 15;
    const int quad = lane >> 4;

    f32x4 acc[4][4];
#pragma unroll
    for (int i = 0; i < 4; ++i)
#pragma unroll
        for (int j = 0; j < 4; ++j)
            acc[i][j] = (f32x4){0.f, 0.f, 0.f, 0.f};

    const float* xg = x + (size_t)srow * KK + kbase + scol;
    const float* wg = w + (size_t)(n0 + srow) * KK + kbase + scol;
    __hip_bfloat16* lxw = &lx[srow * LDSP + scol];
    __hip_bfloat16* lww = &lw[srow * LDSP + scol];

    for (int kt = 0; kt < KPB / KT; ++kt) {
        // ---- global load: 32 fp32 of x + 32 of w per thread ----
        float4 xv[8], wv[8];
        const float4* xg4 = (const float4*)(xg + kt * KT);
        const float4* wg4 = (const float4*)(wg + kt * KT);
#pragma unroll
        for (int i = 0; i < 8; ++i) xv[i] = xg4[i];
#pragma unroll
        for (int i = 0; i < 8; ++i) wv[i] = wg4[i];

        __syncthreads();   // previous iteration's LDS frag reads done

        // ---- cvt fp32 -> bf16, stage as 16B rows ----
#pragma unroll
        for (int h = 0; h < 4; ++h) {
            union { __hip_bfloat16 b[8]; uint4 u; } px, pw;
            const float* fx = (const float*)&xv[2 * h];
            const float* fw = (const float*)&wv[2 * h];
#pragma unroll
            for (int j = 0; j < 8; ++j) {
                px.b[j] = __float2bfloat16(fx[j]);
                pw.b[j] = __float2bfloat16(fw[j]);
            }
            *(uint4*)(lxw + 8 * h) = px.u;
            *(uint4*)(lww + 8 * h) = pw.u;
        }

        __syncthreads();

        // ---- 2 k-steps x 16 MFMAs ----
#pragma unroll
        for (int kk = 0; kk < 2; ++kk) {
            const int kcol = kk * 32 + quad * 8;
            bf16x8 af[4], bw[4];
#pragma unroll
            for (int i = 0; i < 4; ++i) {
                af[i] = *(const bf16x8*)&lx[(wm0 + i * 16 + l16) * LDSP + kcol];
                bw[i] = *(const bf16x8*)&lw[(wn0 + i * 16 + l16) * LDSP + kcol];
            }
#pragma unroll
            for (int i = 0; i < 4; ++i)
#pragma unroll
                for (int j = 0; j < 4; ++j)
                    acc[i][j] = __builtin_amdgcn_mfma_f32_16x16x32_bf16(
                        af[i], bw[j], acc[i][j], 0, 0, 0);
        }
    }

    // ---- load scale/bias with probed pointers/dtype ----
    __syncthreads();
    const float* scalep = s_c1_is_scale ? c1 : c2;
    const void*  biasp  = s_c1_is_scale ? (const void*)c2 : (const void*)c1;
    if (tid < NT) {
        s_scale[tid] = scalep[n0 + tid];
        float b = 0.0f;
        if (kz == 0) {
            if (s_bias_kind == 0)      b = __half2float(((const __half*)biasp)[n0 + tid]);
            else if (s_bias_kind == 1) b = __bfloat162float(((const __hip_bfloat16*)biasp)[n0 + tid]);
            else                       b = ((const float*)biasp)[n0 + tid];
        }
        s_bias[tid] = b;
    }
    __syncthreads();

    // ---- epilogue: scale, bias (kz==0), device-scope atomic combine ----
#pragma unroll
    for (int j = 0; j < 4; ++j) {
        const int nl = wn0 + j * 16 + l16;
        const float sc = s_scale[nl];
        const float bs = s_bias[nl];
#pragma unroll
        for (int i = 0; i < 4; ++i) {
            const int mb = wm0 + i * 16 + quad * 4;
#pragma unroll
            for (int r = 0; r < 4; ++r) {
                atomicAdd(out + (size_t)(mb + r) * NN + n0 + nl, acc[i][j][r] * sc + bs);
            }
        }
    }
}

extern "C" void kernel_launch(void* const* d_in, const int* in_sizes, int n_in,
                              void* d_out, int out_size, void* d_ws, size_t ws_size,
                              hipStream_t stream) {
    // Size-RANK input ID (verbatim from passing R4): largest = weight,
    // 2nd largest = x, remaining two = {scale, bias} (probed on device).
    int iw = 0;
    for (int i = 1; i < n_in; ++i) if (in_sizes[i] > in_sizes[iw]) iw = i;
    int ix = -1;
    for (int i = 0; i < n_in; ++i)
        if (i != iw && (ix < 0 || in_sizes[i] > in_sizes[ix])) ix = i;
    const float* c1 = nullptr;
    const float* c2 = nullptr;
    for (int i = 0; i < n_in; ++i) {
        if (i == iw || i == ix) continue;
        if (!c1) c1 = (const float*)d_in[i];
        else     c2 = (const float*)d_in[i];
    }
    const float* w = (const float*)d_in[iw];
    const float* x = (const float*)d_in[ix];
    float* out = (float*)d_out;

    // out is an atomic accumulation target: zero it (harness poisons with 0xAA)
    hipMemsetAsync(d_out, 0, (size_t)out_size * sizeof(float), stream);

    dim3 grid(NN / NT, KSPLIT);
    cfp8lin_mfma<<<grid, dim3(256, 1, 1), 0, stream>>>(x, w, c1, c2, out);
}

// Round 6
// 439.522 us; speedup vs baseline: 1.6625x; 1.0417x over previous
//
#include <hip/hip_runtime.h>
#include <hip/hip_bf16.h>
#include <hip/hip_fp16.h>

// CompressedFP8Linear: out[128,8192] = x[128,8192] @ (w*scale)[8192,8192]^T + bias
//
// R6 journal:
//  - R5 passed (194us kernel) but latency-bound: HBM 14%, MfmaUtil 3.4%,
//    VALU 2.3%, occ 20%. Full vmcnt drain per iter + 2 blocks/CU.
//  - R6: (1) 4 blocks/CU (NT=64, 1024 blocks, launch_bounds(256,4));
//    (2) register prefetch of tile kt+1 across the barrier (reg-dest loads
//    don't drain at s_barrier); (3) one barrier/iter via double-buffered LDS.
//  - Input ID (R4-verified, verbatim): size-RANK largest=weight, 2nd=x;
//    scale-vs-bias + bias dtype probed on device by content.
//  - Numerics: scale<=0.02 -> single bf16 pass error ~0.007 << thr 0.147.
//  - Floor: 272 MB / 6.3 TB/s ~= 43 us.

namespace {
constexpr int NN = 8192;
constexpr int KK = 8192;
constexpr int MT = 128;            // m tile = all of M
constexpr int NT = 64;             // n tile
constexpr int KSPLIT = 8;          // k-split over blockIdx.y, atomic combine
constexpr int KPB = KK / KSPLIT;   // 1024
constexpr int KT = 32;             // k staged per iteration
constexpr int NIT = KPB / KT;      // 32 iterations
constexpr int LDSP = KT + 8;       // 40 elts = 80 B rows; b128 frag reads aligned

typedef __attribute__((ext_vector_type(8))) short bf16x8;
typedef __attribute__((ext_vector_type(4))) float f32x4;
}

__global__ __launch_bounds__(256, 4)
void cfp8lin_mfma2(const float* __restrict__ x, const float* __restrict__ w,
                   const float* __restrict__ c1, const float* __restrict__ c2,
                   float* __restrict__ out)
{
    __shared__ __align__(16) __hip_bfloat16 lx[2][MT * LDSP];  // 2x10240 B
    __shared__ __align__(16) __hip_bfloat16 lw[2][NT * LDSP];  // 2x5120 B
    __shared__ float s_scale[NT];
    __shared__ float s_bias[NT];
    __shared__ int s_c1_is_scale;
    __shared__ int s_bias_kind;        // 0=f16, 1=bf16, 2=f32

    const int tid = threadIdx.x;
    const int n0 = blockIdx.x * NT;
    const int kz = blockIdx.y;
    const size_t kbase = (size_t)kz * KPB;

    // ---- runtime content probes (verbatim from passing R4/R5) ----
    if (tid == 0) {
        int ok1 = 1;
        for (int i = 0; i < 64; ++i) {
            float v = c1[i * 64];
            if (!(v > 1e-4f && v < 0.5f)) { ok1 = 0; break; }
        }
        s_c1_is_scale = ok1;
        const void* bp = ok1 ? (const void*)c2 : (const void*)c1;
        int kind = 2;
        {
            const __half* h = (const __half*)bp;
            int good = 1;
            for (int i = 0; i < 64; ++i) {
                float v = __half2float(h[i * 64]);
                if (!(v < 0.5f && v > -0.5f)) { good = 0; break; }
            }
            if (good) kind = 0;
        }
        if (kind == 2) {
            const __hip_bfloat16* h = (const __hip_bfloat16*)bp;
            int good = 1;
            for (int i = 0; i < 64; ++i) {
                float v = __bfloat162float(h[i * 64]);
                if (!(v < 0.5f && v > -0.5f)) { good = 0; break; }
            }
            if (good) kind = 1;
        }
        s_bias_kind = kind;
    }

    // ---- staging map: 8 lanes per row (128 B contiguous), 32 rows/instr ----
    const int lrow = tid >> 3;         // 0..31
    const int lc4  = tid & 7;          // float4 column
    const float* xg = x + (size_t)lrow * KK + kbase + lc4 * 4;
    const float* wg = w + (size_t)(n0 + lrow) * KK + kbase + lc4 * 4;

    float4 xv[4], wv[2];
    auto load_tile = [&](int kt) {
        const size_t ko = (size_t)kt * KT;
#pragma unroll
        for (int i = 0; i < 4; ++i)
            xv[i] = *(const float4*)(xg + (size_t)(i * 32) * KK + ko);
#pragma unroll
        for (int i = 0; i < 2; ++i)
            wv[i] = *(const float4*)(wg + (size_t)(i * 32) * KK + ko);
    };

    load_tile(0);   // prologue prefetch

    // ---- compute map: 4 waves, each 32(m) x 64(n) ----
    const int lane = tid & 63;
    const int wid  = tid >> 6;
    const int wm0  = wid * 32;
    const int l16  = lane & 15;
    const int quad = lane >> 4;
    const int kcol = quad * 8;

    f32x4 acc[2][4];
#pragma unroll
    for (int i = 0; i < 2; ++i)
#pragma unroll
        for (int j = 0; j < 4; ++j)
            acc[i][j] = (f32x4){0.f, 0.f, 0.f, 0.f};

    for (int kt = 0; kt < NIT; ++kt) {
        const int buf = kt & 1;

        // ---- stage current tile (vmcnt wait lands here, one iter late) ----
#pragma unroll
        for (int i = 0; i < 4; ++i) {
            union { __hip_bfloat16 b[4]; uint2 u; } p;
            p.b[0] = __float2bfloat16(xv[i].x);
            p.b[1] = __float2bfloat16(xv[i].y);
            p.b[2] = __float2bfloat16(xv[i].z);
            p.b[3] = __float2bfloat16(xv[i].w);
            *(uint2*)&lx[buf][(i * 32 + lrow) * LDSP + lc4 * 4] = p.u;
        }
#pragma unroll
        for (int i = 0; i < 2; ++i) {
            union { __hip_bfloat16 b[4]; uint2 u; } p;
            p.b[0] = __float2bfloat16(wv[i].x);
            p.b[1] = __float2bfloat16(wv[i].y);
            p.b[2] = __float2bfloat16(wv[i].z);
            p.b[3] = __float2bfloat16(wv[i].w);
            *(uint2*)&lw[buf][(i * 32 + lrow) * LDSP + lc4 * 4] = p.u;
        }

        // ---- prefetch next tile into regs (stays in flight across barrier;
        //      last iter harmlessly reloads tile 0 to avoid OOB) ----
        load_tile((kt + 1 < NIT) ? (kt + 1) : 0);

        __syncthreads();

        // ---- compute on buf ----
        bf16x8 af[2], bw[4];
#pragma unroll
        for (int i = 0; i < 2; ++i)
            af[i] = *(const bf16x8*)&lx[buf][(wm0 + i * 16 + l16) * LDSP + kcol];
#pragma unroll
        for (int j = 0; j < 4; ++j)
            bw[j] = *(const bf16x8*)&lw[buf][(j * 16 + l16) * LDSP + kcol];
#pragma unroll
        for (int i = 0; i < 2; ++i)
#pragma unroll
            for (int j = 0; j < 4; ++j)
                acc[i][j] = __builtin_amdgcn_mfma_f32_16x16x32_bf16(
                    af[i], bw[j], acc[i][j], 0, 0, 0);
    }

    // ---- scale/bias via probed pointers ----
    __syncthreads();
    const float* scalep = s_c1_is_scale ? c1 : c2;
    const void*  biasp  = s_c1_is_scale ? (const void*)c2 : (const void*)c1;
    if (tid < NT) {
        s_scale[tid] = scalep[n0 + tid];
        float b = 0.0f;
        if (kz == 0) {
            if (s_bias_kind == 0)      b = __half2float(((const __half*)biasp)[n0 + tid]);
            else if (s_bias_kind == 1) b = __bfloat162float(((const __hip_bfloat16*)biasp)[n0 + tid]);
            else                       b = ((const float*)biasp)[n0 + tid];
        }
        s_bias[tid] = b;
    }
    __syncthreads();

    // ---- epilogue: scale, bias (kz==0), atomic combine ----
#pragma unroll
    for (int j = 0; j < 4; ++j) {
        const int nl = j * 16 + l16;
        const float sc = s_scale[nl];
        const float bs = s_bias[nl];
#pragma unroll
        for (int i = 0; i < 2; ++i) {
            const int mb = wm0 + i * 16 + quad * 4;
#pragma unroll
            for (int r = 0; r < 4; ++r) {
                atomicAdd(out + (size_t)(mb + r) * NN + n0 + nl, acc[i][j][r] * sc + bs);
            }
        }
    }
}

extern "C" void kernel_launch(void* const* d_in, const int* in_sizes, int n_in,
                              void* d_out, int out_size, void* d_ws, size_t ws_size,
                              hipStream_t stream) {
    // Size-RANK input ID (R4-verified): largest = weight, 2nd = x,
    // remaining two = {scale, bias} (disambiguated on device).
    int iw = 0;
    for (int i = 1; i < n_in; ++i) if (in_sizes[i] > in_sizes[iw]) iw = i;
    int ix = -1;
    for (int i = 0; i < n_in; ++i)
        if (i != iw && (ix < 0 || in_sizes[i] > in_sizes[ix])) ix = i;
    const float* c1 = nullptr;
    const float* c2 = nullptr;
    for (int i = 0; i < n_in; ++i) {
        if (i == iw || i == ix) continue;
        if (!c1) c1 = (const float*)d_in[i];
        else     c2 = (const float*)d_in[i];
    }
    const float* w = (const float*)d_in[iw];
    const float* x = (const float*)d_in[ix];
    float* out = (float*)d_out;

    hipMemsetAsync(d_out, 0, (size_t)out_size * sizeof(float), stream);

    dim3 grid(NN / NT, KSPLIT);
    cfp8lin_mfma2<<<grid, dim3(256, 1, 1), 0, stream>>>(x, w, c1, c2, out);
}

// Round 7
// 418.440 us; speedup vs baseline: 1.7463x; 1.0504x over previous
//
#include <hip/hip_runtime.h>
#include <hip/hip_bf16.h>
#include <hip/hip_fp16.h>

// CompressedFP8Linear: out[128,8192] = x[128,8192] @ (w*scale)[8192,8192]^T + bias
//
// R7 journal:
//  - R6 post-mortem: VGPR=48 proves the compiler dropped the reg-prefetch
//    across __syncthreads -> every iter serialized on vmcnt(0); barrier
//    lockstep left only 4 independent stall-groups/CU. 176us, HBM 13%.
//  - R7: NO barrier in the K-loop. 4 waves/block fully independent, each with
//    a private LDS w double-buffer (wave-local lgkmcnt ordering only).
//    x is pre-converted to bf16 in MFMA A-frag order into d_ws by a prep
//    kernel (also resolves scale/bias via ballot probes -> no per-block
//    serial probes). Weight streamed in 512B-contiguous runs, KT=128.
//  - Input ID (R4-verified): size-RANK largest=weight, 2nd=x; scale-vs-bias
//    + bias dtype probed by content (lane-parallel).
//  - Floor: 272 MB / 6.3 TB/s ~= 43 us. Fallback to R6 kernel if ws too small.

namespace {
constexpr int MM = 128;
constexpr int NN = 8192;
constexpr int KK = 8192;
constexpr int KSPLIT = 8;
constexpr int KPB = KK / KSPLIT;     // 1024
constexpr int KT = 128;              // k per staged iteration
constexpr int NIT = KPB / KT;        // 8
constexpr int LDSW = KT + 8;         // 136 elts/row: b128 frag reads ~conflict-lite

constexpr size_t WS_SCALE_OFF = 0;                    // 8192 f32
constexpr size_t WS_BIAS_OFF  = 8192 * 4;             // 8192 f32
constexpr size_t WS_XSW_OFF   = 65536;                // 2 MB bf16 swizzled x
constexpr size_t WS_NEED      = WS_XSW_OFF + (size_t)MM * KK * 2;

typedef __attribute__((ext_vector_type(8))) short bf16x8;
typedef __attribute__((ext_vector_type(4))) float f32x4;
}

// ---------------- prep: resolve scale/bias + swizzle x -> A-frag bf16 ----------------
// x_sw layout: uint4 index ((s*8 + t)*64 + l) holds A[m=16t+(l&15)][k=32s+(l>>4)*8+j],
// j=0..7 (exactly the 16x16x32 A-fragment a wave loads per m-tile t, k-step s).
__global__ __launch_bounds__(256)
void cfp8_prep(const float* __restrict__ x,
               const float* __restrict__ c1, const float* __restrict__ c2,
               unsigned char* __restrict__ ws)
{
    const int bid = blockIdx.x;
    const int tid = threadIdx.x;

    if (bid < 32) {
        __shared__ int s_c1s, s_kind;
        if (tid < 64) {
            float v = c1[tid * 64];
            unsigned long long b = __ballot((v > 1e-4f) && (v < 0.5f));
            int c1s = (b == ~0ull) ? 1 : 0;
            const void* bp = c1s ? (const void*)c2 : (const void*)c1;
            float vf = __half2float(((const __half*)bp)[tid * 64]);
            unsigned long long bf_ = __ballot((vf < 0.5f) && (vf > -0.5f));
            float vb = __bfloat162float(((const __hip_bfloat16*)bp)[tid * 64]);
            unsigned long long bb = __ballot((vb < 0.5f) && (vb > -0.5f));
            if (tid == 0) {
                s_c1s  = c1s;
                s_kind = (bf_ == ~0ull) ? 0 : ((bb == ~0ull) ? 1 : 2);
            }
        }
        __syncthreads();
        const float* scalep = s_c1s ? c1 : c2;
        const void*  biasp  = s_c1s ? (const void*)c2 : (const void*)c1;
        const int i = bid * 256 + tid;              // [0, 8192)
        float bsv;
        if (s_kind == 0)      bsv = __half2float(((const __half*)biasp)[i]);
        else if (s_kind == 1) bsv = __bfloat162float(((const __hip_bfloat16*)biasp)[i]);
        else                  bsv = ((const float*)biasp)[i];
        ((float*)(ws + WS_SCALE_OFF))[i] = scalep[i];
        ((float*)(ws + WS_BIAS_OFF))[i]  = bsv;
    } else {
        // x swizzle: thread g handles 8 consecutive fp32 (coalesced 32B read)
        const int g = (bid - 32) * 256 + tid;       // [0, 131072)
        const float4* src = (const float4*)x + (size_t)g * 2;
        float4 a = src[0], b = src[1];
        const int m  = g >> 10;                     // row (K/8 = 1024 groups/row)
        const int kg = g & 1023;
        const int s  = kg >> 2;                     // k-step of 32
        const int r8 = kg & 3;                      // which 8-elt chunk (quad)
        const int t  = m >> 4;
        const int lm = m & 15;
        const int l  = r8 * 16 + lm;
        union { __hip_bfloat16 h[8]; uint4 u; } p;
        p.h[0] = __float2bfloat16(a.x); p.h[1] = __float2bfloat16(a.y);
        p.h[2] = __float2bfloat16(a.z); p.h[3] = __float2bfloat16(a.w);
        p.h[4] = __float2bfloat16(b.x); p.h[5] = __float2bfloat16(b.y);
        p.h[6] = __float2bfloat16(b.z); p.h[7] = __float2bfloat16(b.w);
        ((uint4*)(ws + WS_XSW_OFF))[(size_t)(s * 8 + t) * 64 + l] = p.u;
    }
}

// ---------------- GEMM: barrier-free wave-private pipeline ----------------
__global__ __launch_bounds__(256, 4)
void cfp8_gemm(const float* __restrict__ w, const unsigned char* __restrict__ ws,
               float* __restrict__ out)
{
    // 4 waves x 2 bufs x (16 rows x 136 elts) bf16 = 34,816 B; 4 blocks/CU = 139 KB
    __shared__ __align__(16) __hip_bfloat16 lw[4][2][16 * LDSW];

    const int tid  = threadIdx.x;
    const int lane = tid & 63;
    const int wid  = tid >> 6;
    const int kz   = blockIdx.y;
    const int n0   = blockIdx.x * 64 + wid * 16;    // wave-private 16 n-rows
    const size_t kbase = (size_t)kz * KPB;

    const __hip_bfloat16* xsw = (const __hip_bfloat16*)(ws + WS_XSW_OFF);
    const float* wsc = (const float*)(ws + WS_SCALE_OFF);
    const float* wbs = (const float*)(ws + WS_BIAS_OFF);

    const int l16  = lane & 15;
    const int quad = lane >> 4;

    // epilogue params loaded early (prep ran on same stream)
    const float sc = wsc[n0 + l16];
    const float bs = (kz == 0) ? wbs[n0 + l16] : 0.0f;

    // staging: round i: row = 2i + (lane>>5), fp32 col = (lane&31)*4
    //   -> 32 lanes cover one row's 512B contiguous run
    const int srow = lane >> 5;
    const int scol = (lane & 31) * 4;
    const float* wg = w + (size_t)(n0 + srow) * KK + kbase + scol;

    float4 wf[8];
#pragma unroll
    for (int i = 0; i < 8; ++i)
        wf[i] = *(const float4*)(wg + (size_t)(2 * i) * KK);

    f32x4 acc[8];
#pragma unroll
    for (int t = 0; t < 8; ++t) acc[t] = (f32x4){0.f, 0.f, 0.f, 0.f};

    for (int kt = 0; kt < NIT; ++kt) {
        __hip_bfloat16* lb = &lw[wid][kt & 1][0];

        // ---- stage current w tile (wave-local; lgkmcnt ordering only) ----
#pragma unroll
        for (int i = 0; i < 8; ++i) {
            union { __hip_bfloat16 h[4]; uint2 u; } p;
            p.h[0] = __float2bfloat16(wf[i].x);
            p.h[1] = __float2bfloat16(wf[i].y);
            p.h[2] = __float2bfloat16(wf[i].z);
            p.h[3] = __float2bfloat16(wf[i].w);
            *(uint2*)&lb[(2 * i + srow) * LDSW + scol] = p.u;
        }

        // ---- prefetch next tile into regs (no barrier to defeat it) ----
        if (kt + 1 < NIT) {
            const float* wgn = wg + (size_t)(kt + 1) * KT;
#pragma unroll
            for (int i = 0; i < 8; ++i)
                wf[i] = *(const float4*)(wgn + (size_t)(2 * i) * KK);
        }

        // ---- compute: 4 k-steps x 8 m-tiles ----
        const int sgl0 = kz * 32 + kt * 4;          // global k-step index
#pragma unroll
        for (int ss = 0; ss < 4; ++ss) {
            bf16x8 bfrag = *(const bf16x8*)&lb[l16 * LDSW + ss * 32 + quad * 8];
            const uint4* xp = (const uint4*)xsw + (size_t)(sgl0 + ss) * 8 * 64 + lane;
            bf16x8 af[8];
#pragma unroll
            for (int t = 0; t < 8; ++t) {
                uint4 u = xp[(size_t)t * 64];
                af[t] = *(bf16x8*)&u;
            }
#pragma unroll
            for (int t = 0; t < 8; ++t)
                acc[t] = __builtin_amdgcn_mfma_f32_16x16x32_bf16(
                    af[t], bfrag, acc[t], 0, 0, 0);
        }
    }

    // ---- epilogue: scale, bias (kz==0), atomic combine ----
#pragma unroll
    for (int t = 0; t < 8; ++t) {
#pragma unroll
        for (int r = 0; r < 4; ++r) {
            atomicAdd(out + (size_t)(t * 16 + quad * 4 + r) * NN + n0 + l16,
                      acc[t][r] * sc + bs);
        }
    }
}

// ---------------- fallback (R6, passing): used only if ws too small ----------------
namespace fb {
constexpr int NT = 64;
constexpr int KTf = 32;
constexpr int NITf = KPB / KTf;
constexpr int LDSP = KTf + 8;
}

__global__ __launch_bounds__(256, 4)
void cfp8lin_mfma2(const float* __restrict__ x, const float* __restrict__ w,
                   const float* __restrict__ c1, const float* __restrict__ c2,
                   float* __restrict__ out)
{
    using namespace fb;
    __shared__ __align__(16) __hip_bfloat16 lx[2][MM * LDSP];
    __shared__ __align__(16) __hip_bfloat16 lw[2][NT * LDSP];
    __shared__ float s_scale[NT];
    __shared__ float s_bias[NT];
    __shared__ int s_c1_is_scale;
    __shared__ int s_bias_kind;

    const int tid = threadIdx.x;
    const int n0 = blockIdx.x * NT;
    const int kz = blockIdx.y;
    const size_t kbase = (size_t)kz * KPB;

    if (tid < 64) {
        float v = c1[tid * 64];
        unsigned long long b = __ballot((v > 1e-4f) && (v < 0.5f));
        int c1s = (b == ~0ull) ? 1 : 0;
        const void* bp = c1s ? (const void*)c2 : (const void*)c1;
        float vf = __half2float(((const __half*)bp)[tid * 64]);
        unsigned long long bf_ = __ballot((vf < 0.5f) && (vf > -0.5f));
        float vb = __bfloat162float(((const __hip_bfloat16*)bp)[tid * 64]);
        unsigned long long bb = __ballot((vb < 0.5f) && (vb > -0.5f));
        if (tid == 0) {
            s_c1_is_scale = c1s;
            s_bias_kind = (bf_ == ~0ull) ? 0 : ((bb == ~0ull) ? 1 : 2);
        }
    }

    const int lrow = tid >> 3;
    const int lc4  = tid & 7;
    const float* xg = x + (size_t)lrow * KK + kbase + lc4 * 4;
    const float* wg = w + (size_t)(n0 + lrow) * KK + kbase + lc4 * 4;

    float4 xv[4], wv[2];
    auto load_tile = [&](int kt) {
        const size_t ko = (size_t)kt * KTf;
#pragma unroll
        for (int i = 0; i < 4; ++i)
            xv[i] = *(const float4*)(xg + (size_t)(i * 32) * KK + ko);
#pragma unroll
        for (int i = 0; i < 2; ++i)
            wv[i] = *(const float4*)(wg + (size_t)(i * 32) * KK + ko);
    };
    load_tile(0);

    const int lane = tid & 63;
    const int wid  = tid >> 6;
    const int wm0  = wid * 32;
    const int l16  = lane & 15;
    const int quad = lane >> 4;
    const int kcol = quad * 8;

    f32x4 acc[2][4];
#pragma unroll
    for (int i = 0; i < 2; ++i)
#pragma unroll
        for (int j = 0; j < 4; ++j) acc[i][j] = (f32x4){0.f, 0.f, 0.f, 0.f};

    for (int kt = 0; kt < NITf; ++kt) {
        const int buf = kt & 1;
#pragma unroll
        for (int i = 0; i < 4; ++i) {
            union { __hip_bfloat16 b[4]; uint2 u; } p;
            p.b[0] = __float2bfloat16(xv[i].x); p.b[1] = __float2bfloat16(xv[i].y);
            p.b[2] = __float2bfloat16(xv[i].z); p.b[3] = __float2bfloat16(xv[i].w);
            *(uint2*)&lx[buf][(i * 32 + lrow) * LDSP + lc4 * 4] = p.u;
        }
#pragma unroll
        for (int i = 0; i < 2; ++i) {
            union { __hip_bfloat16 b[4]; uint2 u; } p;
            p.b[0] = __float2bfloat16(wv[i].x); p.b[1] = __float2bfloat16(wv[i].y);
            p.b[2] = __float2bfloat16(wv[i].z); p.b[3] = __float2bfloat16(wv[i].w);
            *(uint2*)&lw[buf][(i * 32 + lrow) * LDSP + lc4 * 4] = p.u;
        }
        load_tile((kt + 1 < NITf) ? (kt + 1) : 0);
        __syncthreads();
        bf16x8 af[2], bw[4];
#pragma unroll
        for (int i = 0; i < 2; ++i)
            af[i] = *(const bf16x8*)&lx[buf][(wm0 + i * 16 + l16) * LDSP + kcol];
#pragma unroll
        for (int j = 0; j < 4; ++j)
            bw[j] = *(const bf16x8*)&lw[buf][(j * 16 + l16) * LDSP + kcol];
#pragma unroll
        for (int i = 0; i < 2; ++i)
#pragma unroll
            for (int j = 0; j < 4; ++j)
                acc[i][j] = __builtin_amdgcn_mfma_f32_16x16x32_bf16(
                    af[i], bw[j], acc[i][j], 0, 0, 0);
    }

    __syncthreads();
    const float* scalep = s_c1_is_scale ? c1 : c2;
    const void*  biasp  = s_c1_is_scale ? (const void*)c2 : (const void*)c1;
    if (tid < fb::NT) {
        s_scale[tid] = scalep[n0 + tid];
        float b = 0.0f;
        if (kz == 0) {
            if (s_bias_kind == 0)      b = __half2float(((const __half*)biasp)[n0 + tid]);
            else if (s_bias_kind == 1) b = __bfloat162float(((const __hip_bfloat16*)biasp)[n0 + tid]);
            else                       b = ((const float*)biasp)[n0 + tid];
        }
        s_bias[tid] = b;
    }
    __syncthreads();

#pragma unroll
    for (int j = 0; j < 4; ++j) {
        const int nl = j * 16 + l16;
        const float scv = s_scale[nl];
        const float bsv = s_bias[nl];
#pragma unroll
        for (int i = 0; i < 2; ++i) {
            const int mb = wm0 + i * 16 + quad * 4;
#pragma unroll
            for (int r = 0; r < 4; ++r)
                atomicAdd(out + (size_t)(mb + r) * NN + n0 + nl,
                          acc[i][j][r] * scv + bsv);
        }
    }
}

extern "C" void kernel_launch(void* const* d_in, const int* in_sizes, int n_in,
                              void* d_out, int out_size, void* d_ws, size_t ws_size,
                              hipStream_t stream) {
    // Size-RANK input ID (R4-verified): largest = weight, 2nd = x,
    // remaining two = {scale, bias} (disambiguated on device).
    int iw = 0;
    for (int i = 1; i < n_in; ++i) if (in_sizes[i] > in_sizes[iw]) iw = i;
    int ix = -1;
    for (int i = 0; i < n_in; ++i)
        if (i != iw && (ix < 0 || in_sizes[i] > in_sizes[ix])) ix = i;
    const float* c1 = nullptr;
    const float* c2 = nullptr;
    for (int i = 0; i < n_in; ++i) {
        if (i == iw || i == ix) continue;
        if (!c1) c1 = (const float*)d_in[i];
        else     c2 = (const float*)d_in[i];
    }
    const float* w = (const float*)d_in[iw];
    const float* x = (const float*)d_in[ix];
    float* out = (float*)d_out;

    hipMemsetAsync(d_out, 0, (size_t)out_size * sizeof(float), stream);

    if (ws_size >= WS_NEED && d_ws != nullptr) {
        unsigned char* ws = (unsigned char*)d_ws;
        cfp8_prep<<<dim3(32 + 512), dim3(256), 0, stream>>>(x, c1, c2, ws);
        cfp8_gemm<<<dim3(NN / 64, KSPLIT), dim3(256), 0, stream>>>(w, ws, out);
    } else {
        dim3 grid(NN / fb::NT, KSPLIT);
        cfp8lin_mfma2<<<grid, dim3(256), 0, stream>>>(x, w, c1, c2, out);
    }
}